// Round 3
// baseline (164.124 us; speedup 1.0000x reference)
//
#include <hip/hip_runtime.h>

#define DI static __device__ __forceinline__

typedef short s16x8 __attribute__((ext_vector_type(8)));
typedef float f32x4 __attribute__((ext_vector_type(4)));

DI unsigned short f2b(float f) {
  union { float f; unsigned u; } v; v.f = f;
  return (unsigned short)((v.u + 0x7FFF + ((v.u >> 16) & 1)) >> 16);  // RNE
}
DI float b2f(unsigned short s) {
  union { unsigned u; float f; } v; v.u = ((unsigned)s) << 16;
  return v.f;
}
DI f32x4 MFMA(s16x8 a, s16x8 b, f32x4 c) {
  return __builtin_amdgcn_mfma_f32_16x16x32_bf16(a, b, c, 0, 0, 0);
}
DI s16x8 ldg8(const unsigned short* p) { return *(const s16x8*)p; }

// ---- ws layout (short offsets) ----
#define OFF_WEN   0        // [2048 winT | 8192 wresT] per stack
#define OFF_WAL   10240
#define OFF_WHOW  20480
#define OFF_WHOB  30720
#define OFF_BGEN  40960    // [21][64][32]
#define OFF_BGAL  83968
#define OFF_WIT   126976   // [192][64]
#define OFF_WHT   139264
#define OFF_FC1T  151552   // [64][32]
#define OFF_FC2E  153600   // [16][64] cols:0-5 fc2, 6 how_bout
#define OFF_HOWT  154624   // [64][64]
#define OFF_HOBT  158720   // [16][64] row0 = hob_wout
#define SH_END    159744
// byte offsets
#define B_EMB_EN  (SH_END*2)
#define B_EMB_AL  (B_EMB_EN + 2621440)
#define B_HB      (B_EMB_AL + 2621440)
#define B_GBF     (B_HB + 40960)           // (10240+16) x 64 bf16 (padded)

#define XSTR 40   // x row stride (shorts): 80B -> ~2-way banks on b128
#define HSTR 72   // h row stride (shorts): 144B -> ~2-way banks
#define PSTR 680

// ================= kprep: convert all weights to bf16 MFMA-friendly layouts
__global__ __launch_bounds__(256) void kprep(
    const float* __restrict__ hen_win, const float* __restrict__ hen_wres,
    const float* __restrict__ hal_win, const float* __restrict__ hal_wres,
    const float* __restrict__ how_win, const float* __restrict__ how_wres,
    const float* __restrict__ hob_win, const float* __restrict__ hob_wres,
    const float* __restrict__ hen_wout, const float* __restrict__ hen_bout,
    const float* __restrict__ hal_wout, const float* __restrict__ hal_bout,
    const float* __restrict__ gru_wi, const float* __restrict__ gru_wh,
    const float* __restrict__ fc1_w, const float* __restrict__ fc2_w,
    const float* __restrict__ how_bout, const float* __restrict__ how_wout,
    const float* __restrict__ hob_wout,
    unsigned short* __restrict__ ws)
{
  const int gid = blockIdx.x * 256 + threadIdx.x;
  const int gsz = gridDim.x * 256;
  for (int i = gid; i < 4 * 10240; i += gsz) {
    int s = i / 10240, idx = i - s * 10240;
    const float* win  = (s == 0) ? hen_win  : (s == 1) ? hal_win  : (s == 2) ? how_win  : hob_win;
    const float* wres = (s == 0) ? hen_wres : (s == 1) ? hal_wres : (s == 2) ? how_wres : hob_wres;
    float v;
    if (idx < 2048) { int n = idx >> 5, k = idx & 31; v = (k < 10) ? win[k*64 + n] : 0.f; }
    else { int r = idx - 2048; int d = r >> 12; int r2 = r & 4095; int n = r2 >> 6, k = r2 & 63;
           v = wres[d*4096 + k*64 + n]; }
    ws[s * 10240 + idx] = f2b(v);
  }
  for (int i = gid; i < 2 * 43008; i += gsz) {
    int s = i / 43008, idx = i - s * 43008;
    const float* wout = s ? hal_wout : hen_wout;
    const float* bout = s ? hal_bout : hen_bout;
    int kl = idx & 31, n = (idx >> 5) & 63, c = idx >> 11;
    int kfg = c * 32 + kl;
    float v = 0.f;
    if (kfg < 640)      { int k = kfg / 10, f = kfg - k * 10; v = wout[k*640 + f*64 + n]; }
    else if (kfg < 650) { v = bout[(kfg - 640)*64 + n]; }
    ws[(s ? OFF_BGAL : OFF_BGEN) + idx] = f2b(v);
  }
  for (int i = gid; i < 2 * 12288; i += gsz) {
    int s = i / 12288, idx = i - s * 12288;
    int n = idx >> 6, k = idx & 63;
    const float* w = s ? gru_wh : gru_wi;
    ws[(s ? OFF_WHT : OFF_WIT) + idx] = f2b(w[k*192 + n]);
  }
  for (int i = gid; i < 2048; i += gsz) { int n = i >> 5, k = i & 31; ws[OFF_FC1T + i] = f2b(fc1_w[k*64 + n]); }
  for (int i = gid; i < 1024; i += gsz) {
    int n = i >> 6, k = i & 63;
    float v = 0.f; if (n < 6) v = fc2_w[k*6 + n]; else if (n == 6) v = how_bout[k];
    ws[OFF_FC2E + i] = f2b(v);
  }
  for (int i = gid; i < 4096; i += gsz) ws[OFF_HOWT + i] = f2b(how_wout[i]);
  for (int i = gid; i < 1024; i += gsz) { int n = i >> 6, k = i & 63; ws[OFF_HOBT + i] = f2b(n == 0 ? hob_wout[k] : 0.f); }
}

// ================= barrier-free hypernet stack (wave-local 16-row slabs)
template<int NT>
DI void run_stack(const unsigned short* x_lds, unsigned short* h_lds,
                  const unsigned short* wg, const float* bin, const float* bres,
                  float (&hval)[2][4][4])
{
  const int t = threadIdx.x;
  const int l = t & 63, wv = t >> 6;
  const int lrow = l & 15, lk8 = (l >> 4) * 8, lr4 = (l >> 4) * 4;
  {
    s16x8 bw[4]; float bb0[4];
#pragma unroll
    for (int nt = 0; nt < 4; nt++) { bw[nt] = ldg8(wg + (nt*16 + lrow)*32 + lk8); bb0[nt] = bin[nt*16 + lrow]; }
#pragma unroll
    for (int i = 0; i < 2; i++) {
      int mf = wv + i * 4;
      if (mf < NT) {
        s16x8 a = *(const s16x8*)&x_lds[(mf*16 + lrow)*XSTR + lk8];
#pragma unroll
        for (int nt = 0; nt < 4; nt++) {
          f32x4 d = MFMA(a, bw[nt], f32x4{0.f,0.f,0.f,0.f});
#pragma unroll
          for (int r = 0; r < 4; r++) hval[i][nt][r] = fmaxf(d[r] + bb0[nt], 0.f);
        }
#pragma unroll
        for (int nt = 0; nt < 4; nt++)
#pragma unroll
          for (int r = 0; r < 4; r++)
            h_lds[(mf*16 + lr4 + r)*HSTR + nt*16 + lrow] = f2b(hval[i][nt][r]);
      }
    }
  }
#pragma unroll
  for (int d = 0; d < 2; d++) {
    const unsigned short* wt = wg + 2048 + d * 4096;
    s16x8 bwr[4][2]; float bbr[4];
#pragma unroll
    for (int nt = 0; nt < 4; nt++) {
      bbr[nt] = bres[d*64 + nt*16 + lrow];
      bwr[nt][0] = ldg8(wt + (nt*16 + lrow)*64 + lk8);
      bwr[nt][1] = ldg8(wt + (nt*16 + lrow)*64 + 32 + lk8);
    }
#pragma unroll
    for (int i = 0; i < 2; i++) {
      int mf = wv + i * 4;
      if (mf < NT) {
        s16x8 af0 = *(const s16x8*)&h_lds[(mf*16 + lrow)*HSTR + lk8];
        s16x8 af1 = *(const s16x8*)&h_lds[(mf*16 + lrow)*HSTR + 32 + lk8];
#pragma unroll
        for (int nt = 0; nt < 4; nt++) {
          f32x4 acc = MFMA(af0, bwr[nt][0], f32x4{0.f,0.f,0.f,0.f});
          acc = MFMA(af1, bwr[nt][1], acc);
#pragma unroll
          for (int r = 0; r < 4; r++) hval[i][nt][r] = fmaxf(acc[r] + bbr[nt], 0.f) + hval[i][nt][r];
        }
#pragma unroll
        for (int nt = 0; nt < 4; nt++)
#pragma unroll
          for (int r = 0; r < 4; r++)
            h_lds[(mf*16 + lr4 + r)*HSTR + nt*16 + lrow] = f2b(hval[i][nt][r]);
      }
    }
  }
}

// ================= khyp_ea body: stack + P-build + N-split GEMM -> emb (8 agents/block)
template<int E, int NT>
DI void hyp_body(const float* __restrict__ feats,
                 const unsigned short* __restrict__ Wg, const unsigned short* __restrict__ Bg,
                 const float* __restrict__ bin, const float* __restrict__ bres,
                 float* __restrict__ emb,
                 unsigned short* x_lds, unsigned short* h_lds, unsigned short* P)
{
  const int t = threadIdx.x;
  const int l = t & 63, wv = t >> 6;
  const int lrow = l & 15, lk8 = (l >> 4) * 8, lr4 = (l >> 4) * 4;
  constexpr int MT = E * 8;

  for (int idx = t; idx < 96*32; idx += 256) {
    int row = idx >> 5, c = idx & 31;
    float v = (c < 10 && row < MT) ? feats[row*10 + c] : 0.f;
    x_lds[row*XSTR + c] = f2b(v);
  }
  __syncthreads();

  float hval[2][4][4];
  run_stack<NT>(x_lds, h_lds, Wg, bin, bres, hval);
  __syncthreads();   // h complete across waves (P-build reads all rows)

  // ---- P-build: thread -> (agent a = t>>5, k pair k2, k2+1)
  const int a = t >> 5, k2 = (t & 31) * 2, fx = t & 31;
  float p0[10], p1[10], sxv = 0.f;
#pragma unroll
  for (int f = 0; f < 10; f++) { p0[f] = 0.f; p1[f] = 0.f; }
#pragma unroll
  for (int e = 0; e < E; e++) {
    int row = a * E + e;
    const unsigned short* xr = x_lds + row * XSTR;
    s16x8 xv8 = *(const s16x8*)xr;
    unsigned xv2 = *(const unsigned*)(xr + 8);
    float xf[10];
#pragma unroll
    for (int f = 0; f < 8; f++) xf[f] = b2f((unsigned short)xv8[f]);
    xf[8] = b2f((unsigned short)(xv2 & 0xFFFF));
    xf[9] = b2f((unsigned short)(xv2 >> 16));
    unsigned hp = *(const unsigned*)&h_lds[row*HSTR + k2];
    float h0 = b2f((unsigned short)(hp & 0xFFFF));
    float h1 = b2f((unsigned short)(hp >> 16));
#pragma unroll
    for (int f = 0; f < 10; f++) { p0[f] += h0 * xf[f]; p1[f] += h1 * xf[f]; }
    if (fx < 10) sxv += xf[fx];
  }
  __syncthreads();   // all x/h reads done before P overwrites that LDS
  unsigned* Pw = (unsigned*)(P + a*PSTR + k2*10);
#pragma unroll
  for (int j = 0; j < 5; j++) Pw[j]     = (unsigned)f2b(p0[2*j]) | ((unsigned)f2b(p0[2*j+1]) << 16);
#pragma unroll
  for (int j = 0; j < 5; j++) Pw[5 + j] = (unsigned)f2b(p1[2*j]) | ((unsigned)f2b(p1[2*j+1]) << 16);
  if (fx < 10) P[a*PSTR + 640 + fx] = f2b(sxv);
  __syncthreads();   // P ready

  // ---- GEMM: wave wv owns N-tile wv (16 cols), all 21 chunks; B direct from global
  const int arow = lrow & 7;     // rows 8..15 duplicate agents (discarded)
  const unsigned short* Bw = Bg + (wv*16 + lrow)*32 + lk8;
  f32x4 acc0 = {0.f,0.f,0.f,0.f}, acc1 = {0.f,0.f,0.f,0.f};
  s16x8 aC = *(const s16x8*)&P[arow*PSTR + lk8];
  s16x8 bC = ldg8(Bw);
#pragma unroll
  for (int c = 0; c < 21; c++) {
    s16x8 aN = aC, bN = bC;
    if (c < 20) {
      aN = *(const s16x8*)&P[arow*PSTR + (c+1)*32 + lk8];
      bN = ldg8(Bw + (c+1)*2048);
    }
    if (c & 1) acc1 = MFMA(aC, bC, acc1); else acc0 = MFMA(aC, bC, acc0);
    aC = aN; bC = bN;
  }
  if (l < 32) {
#pragma unroll
    for (int r = 0; r < 4; r++)
      emb[(lr4 + r)*64 + wv*16 + lrow] = acc0[r] + acc1[r];
  }
}

__global__ __launch_bounds__(256, 5) void khyp_ea(
    const float* __restrict__ en_feats, const float* __restrict__ al_feats,
    const unsigned short* __restrict__ ws,
    const float* __restrict__ en_bin, const float* __restrict__ en_bres,
    const float* __restrict__ al_bin, const float* __restrict__ al_bres,
    float* __restrict__ emb_en, float* __restrict__ emb_al)
{
  __shared__ __align__(16) char smem[21504];
  unsigned short* x_lds = (unsigned short*)smem;            // [96][40]
  unsigned short* h_lds = (unsigned short*)(smem + 7680);   // [96][72]
  unsigned short* P     = (unsigned short*)smem;            // [8][680] overlay
  if (blockIdx.x < 1280) {
    int blk = blockIdx.x;
    hyp_body<11,6>(en_feats + blk*880, ws + OFF_WEN, ws + OFF_BGEN,
                   en_bin, en_bres, emb_en + blk*512, x_lds, h_lds, P);
  } else {
    int blk = blockIdx.x - 1280;
    hyp_body<9,5>(al_feats + blk*720, ws + OFF_WAL, ws + OFF_BGAL,
                  al_bin, al_bres, emb_al + blk*512, x_lds, h_lds, P);
  }
}

// ================= kfused: fc1 + embeds + GRU + fc2/hb + g  (all MFMA, 16 agents/block)
__global__ __launch_bounds__(256) void kfused(
    const float* __restrict__ own, const float* __restrict__ agent_emb,
    const float* __restrict__ action_emb,
    const int* __restrict__ agent_idx, const int* __restrict__ last_action,
    const float* __restrict__ emb_en, const float* __restrict__ emb_al,
    const float* __restrict__ hidden,
    const unsigned short* __restrict__ ws,
    const float* __restrict__ fc1_b, const float* __restrict__ bi,
    const float* __restrict__ bh, const float* __restrict__ fc2_b,
    float* __restrict__ qout, float* __restrict__ hhout,
    unsigned short* __restrict__ g_bf, float* __restrict__ hb)
{
  __shared__ unsigned short own_lds[16*32];
  __shared__ unsigned short x_lds[16*HSTR];
  __shared__ unsigned short hp_lds[16*HSTR];
  __shared__ unsigned short hh_lds[16*HSTR];
  const int t = threadIdx.x;
  const int l = t & 63, wv = t >> 6;
  const int lrow = l & 15, lk8 = (l >> 4) * 8, lr4 = (l >> 4) * 4;
  const int n0 = blockIdx.x * 16;

  const unsigned short* fc1T = ws + OFF_FC1T;
  const unsigned short* wiT  = ws + OFF_WIT;
  const unsigned short* whT  = ws + OFF_WHT;
  const unsigned short* howT = ws + OFF_HOWT;
  const unsigned short* fc2e = ws + OFF_FC2E;

  for (int i = t; i < 512; i += 256) own_lds[i] = f2b(own[n0*32 + i]);
  for (int i = t; i < 1024; i += 256) hp_lds[(i >> 6)*HSTR + (i & 63)] = f2b(hidden[n0*64 + i]);
  __syncthreads();

  const int j = wv * 16 + lrow;
  {  // fc1 + gathers -> x
    s16x8 a0 = *(const s16x8*)&own_lds[lrow*32 + lk8];
    s16x8 b0 = ldg8(fc1T + (wv*16 + lrow)*32 + lk8);
    f32x4 c0 = MFMA(a0, b0, f32x4{0.f,0.f,0.f,0.f});
    float fb = fc1_b[j];
#pragma unroll
    for (int r = 0; r < 4; r++) {
      int aa = lr4 + r; int n = n0 + aa;
      int ai = agent_idx[n], la = last_action[n];
      float v = c0[r] + fb + agent_emb[ai*64 + j] + action_emb[la*64 + j]
              + emb_en[n*64 + j] + emb_al[n*64 + j];
      x_lds[aa*HSTR + j] = f2b(fmaxf(v, 0.f));
    }
  }
  __syncthreads();

  {  // GRU
    s16x8 xa[2], ha[2];
#pragma unroll
    for (int s = 0; s < 2; s++) {
      xa[s] = *(const s16x8*)&x_lds[lrow*HSTR + s*32 + lk8];
      ha[s] = *(const s16x8*)&hp_lds[lrow*HSTR + s*32 + lk8];
    }
    f32x4 gi[3], gh[3];
#pragma unroll
    for (int g3 = 0; g3 < 3; g3++) { gi[g3] = f32x4{0.f,0.f,0.f,0.f}; gh[g3] = f32x4{0.f,0.f,0.f,0.f}; }
#pragma unroll
    for (int g3 = 0; g3 < 3; g3++) {
      int tl = wv + g3 * 4;
#pragma unroll
      for (int s = 0; s < 2; s++) {
        gi[g3] = MFMA(xa[s], ldg8(wiT + (tl*16 + lrow)*64 + s*32 + lk8), gi[g3]);
        gh[g3] = MFMA(ha[s], ldg8(whT + (tl*16 + lrow)*64 + s*32 + lk8), gh[g3]);
      }
    }
    float bir = bi[j], biz = bi[64 + j], bin_ = bi[128 + j];
    float bhr = bh[j], bhz = bh[64 + j], bhn = bh[128 + j];
#pragma unroll
    for (int r = 0; r < 4; r++) {
      int aa = lr4 + r; int n = n0 + aa;
      float rr = 1.f / (1.f + __expf(-(gi[0][r] + bir + gh[0][r] + bhr)));
      float zz = 1.f / (1.f + __expf(-(gi[1][r] + biz + gh[1][r] + bhz)));
      float nn = tanhf(gi[2][r] + bin_ + rr * (gh[2][r] + bhn));
      float hp = hidden[n*64 + j];
      float hhv = (1.f - zz) * nn + zz * hp;
      hhout[n*64 + j] = hhv;
      hh_lds[aa*HSTR + j] = f2b(hhv);
    }
  }
  __syncthreads();

  {  // g = hh @ howT ; fc2ext (q_normal + hb)
    s16x8 hha[2];
#pragma unroll
    for (int s = 0; s < 2; s++) hha[s] = *(const s16x8*)&hh_lds[lrow*HSTR + s*32 + lk8];
    f32x4 gc = {0.f,0.f,0.f,0.f};
#pragma unroll
    for (int s = 0; s < 2; s++) gc = MFMA(hha[s], ldg8(howT + (wv*16 + lrow)*64 + s*32 + lk8), gc);
#pragma unroll
    for (int r = 0; r < 4; r++) g_bf[(n0 + lr4 + r)*64 + wv*16 + lrow] = f2b(gc[r]);
    if (wv == 0) {
      f32x4 qc = {0.f,0.f,0.f,0.f};
#pragma unroll
      for (int s = 0; s < 2; s++) qc = MFMA(hha[s], ldg8(fc2e + lrow*64 + s*32 + lk8), qc);
#pragma unroll
      for (int r = 0; r < 4; r++) {
        int n = n0 + lr4 + r;
        if (lrow < 6)       qout[n*17 + lrow] = qc[r] + fc2_b[lrow];
        else if (lrow == 6) hb[n] = qc[r];
      }
    }
  }
}

// ================= kattack: hob stack -> qB(regs); how stack -> q_attack (8 agents/block)
__global__ __launch_bounds__(256, 5) void kattack(
    const float* __restrict__ en_feats, const unsigned short* __restrict__ ws,
    const float* __restrict__ how_bin, const float* __restrict__ how_bres,
    const float* __restrict__ hob_bin, const float* __restrict__ hob_bres,
    const unsigned short* __restrict__ g_bf, const float* __restrict__ hb,
    const float* __restrict__ hob_bout, float* __restrict__ qout)
{
  __shared__ __align__(16) char smem[21504];
  unsigned short* x_lds = (unsigned short*)smem;            // [96][40]
  unsigned short* h_lds = (unsigned short*)(smem + 7680);   // [96][72]
  const int t = threadIdx.x;
  const int l = t & 63, wv = t >> 6;
  const int lrow = l & 15, lk8 = (l >> 4) * 8, lr4 = (l >> 4) * 4;
  const int blk = blockIdx.x;
  const float* feats = en_feats + blk * 880;

  for (int idx = t; idx < 96*32; idx += 256) {
    int row = idx >> 5, c = idx & 31;
    float v = (c < 10 && row < 88) ? feats[row*10 + c] : 0.f;
    x_lds[row*XSTR + c] = f2b(v);
  }
  __syncthreads();   // the ONLY barrier

  float hval[2][4][4];
  run_stack<6>(x_lds, h_lds, ws + OFF_WHOB, hob_bin, hob_bres, hval);
  float qb[2][4];
#pragma unroll
  for (int i = 0; i < 2; i++) {
    int mf = wv + i * 4;
    if (mf < 6) {
      s16x8 a0 = *(const s16x8*)&h_lds[(mf*16 + lrow)*HSTR + lk8];
      s16x8 a1 = *(const s16x8*)&h_lds[(mf*16 + lrow)*HSTR + 32 + lk8];
      f32x4 qc = MFMA(a0, ldg8(ws + OFF_HOBT + lrow*64 + lk8), f32x4{0.f,0.f,0.f,0.f});
      qc = MFMA(a1, ldg8(ws + OFF_HOBT + lrow*64 + 32 + lk8), qc);
#pragma unroll
      for (int r = 0; r < 4; r++) qb[i][r] = qc[r];   // col value; col0 (lrow==0) is qB
    }
  }
  run_stack<6>(x_lds, h_lds, ws + OFF_WHOW, how_bin, how_bres, hval);

  float hob_b0 = hob_bout[0];
#pragma unroll
  for (int i = 0; i < 2; i++) {
    int mf = wv + i * 4;
    if (mf < 6) {
      s16x8 a0 = *(const s16x8*)&h_lds[(mf*16 + lrow)*HSTR + lk8];
      s16x8 a1 = *(const s16x8*)&h_lds[(mf*16 + lrow)*HSTR + 32 + lk8];
      f32x4 qc = MFMA(a0, ldg8(g_bf + ((long)blk*8 + lrow)*64 + lk8), f32x4{0.f,0.f,0.f,0.f});
      qc = MFMA(a1, ldg8(g_bf + ((long)blk*8 + lrow)*64 + 32 + lk8), qc);
#pragma unroll
      for (int r = 0; r < 4; r++) {
        int row = mf*16 + lr4 + r;
        int ag = row / 11;
        float qBv = __shfl(qb[i][r], l & 48, 64);   // broadcast col-0 lane
        if (row < 88 && ag == lrow) {
          int n = blk*8 + ag;
          qout[n*17 + 6 + (row - ag*11)] = qc[r] + qBv + hb[n] + hob_b0;
        }
      }
    }
  }
}

extern "C" void kernel_launch(void* const* d_in, const int* in_sizes, int n_in,
                              void* d_out, int out_size, void* d_ws, size_t ws_size,
                              hipStream_t stream)
{
  (void)in_sizes; (void)n_in; (void)out_size; (void)ws_size;
  const float* own        = (const float*)d_in[0];
  const float* enemy      = (const float*)d_in[1];
  const float* ally       = (const float*)d_in[2];
  const float* hidden     = (const float*)d_in[3];
  const float* fc1_w      = (const float*)d_in[4];
  const float* fc1_b      = (const float*)d_in[5];
  const float* agent_emb  = (const float*)d_in[6];
  const float* action_emb = (const float*)d_in[7];
  const float* hen_win  = (const float*)d_in[8];  const float* hen_bin  = (const float*)d_in[9];
  const float* hen_wres = (const float*)d_in[10]; const float* hen_bres = (const float*)d_in[11];
  const float* hen_wout = (const float*)d_in[12]; const float* hen_bout = (const float*)d_in[13];
  const float* hal_win  = (const float*)d_in[14]; const float* hal_bin  = (const float*)d_in[15];
  const float* hal_wres = (const float*)d_in[16]; const float* hal_bres = (const float*)d_in[17];
  const float* hal_wout = (const float*)d_in[18]; const float* hal_bout = (const float*)d_in[19];
  const float* gru_wi = (const float*)d_in[20];   const float* gru_wh = (const float*)d_in[21];
  const float* gru_bi = (const float*)d_in[22];   const float* gru_bh = (const float*)d_in[23];
  const float* fc2_w  = (const float*)d_in[24];   const float* fc2_b  = (const float*)d_in[25];
  const float* how_win  = (const float*)d_in[26]; const float* how_bin  = (const float*)d_in[27];
  const float* how_wres = (const float*)d_in[28]; const float* how_bres = (const float*)d_in[29];
  const float* how_wout = (const float*)d_in[30]; const float* how_bout = (const float*)d_in[31];
  const float* hob_win  = (const float*)d_in[32]; const float* hob_bin  = (const float*)d_in[33];
  const float* hob_wres = (const float*)d_in[34]; const float* hob_bres = (const float*)d_in[35];
  const float* hob_wout = (const float*)d_in[36]; const float* hob_bout = (const float*)d_in[37];
  const int* agent_idx   = (const int*)d_in[38];
  const int* last_action = (const int*)d_in[39];

  unsigned short* ws = (unsigned short*)d_ws;
  float* emb_en = (float*)((char*)d_ws + B_EMB_EN);
  float* emb_al = (float*)((char*)d_ws + B_EMB_AL);
  float* hb     = (float*)((char*)d_ws + B_HB);
  unsigned short* g_bf = (unsigned short*)((char*)d_ws + B_GBF);

  float* q  = (float*)d_out;
  float* hh = q + 1024*10*17;

  kprep<<<128, 256, 0, stream>>>(hen_win, hen_wres, hal_win, hal_wres,
      how_win, how_wres, hob_win, hob_wres,
      hen_wout, hen_bout, hal_wout, hal_bout,
      gru_wi, gru_wh, fc1_w, fc2_w, how_bout, how_wout, hob_wout, ws);
  khyp_ea<<<2560, 256, 0, stream>>>(enemy, ally, ws,
      hen_bin, hen_bres, hal_bin, hal_bres, emb_en, emb_al);
  kfused<<<640, 256, 0, stream>>>(own, agent_emb, action_emb, agent_idx, last_action,
      emb_en, emb_al, hidden, ws, fc1_b, gru_bi, gru_bh, fc2_b, q, hh, g_bf, hb);
  kattack<<<1280, 256, 0, stream>>>(enemy, ws, how_bin, how_bres, hob_bin, hob_bres,
      g_bf, hb, hob_bout, q);
}

// Round 4
// 106.354 us; speedup vs baseline: 1.5432x; 1.5432x over previous
//
#include <hip/hip_runtime.h>

#define DI static __device__ __forceinline__

typedef short s16x8 __attribute__((ext_vector_type(8)));
typedef float f32x4 __attribute__((ext_vector_type(4)));

DI unsigned short f2b(float f) {
  union { float f; unsigned u; } v; v.f = f;
  return (unsigned short)((v.u + 0x7FFF + ((v.u >> 16) & 1)) >> 16);  // RNE
}
DI float b2f(unsigned short s) {
  union { unsigned u; float f; } v; v.u = ((unsigned)s) << 16;
  return v.f;
}
DI f32x4 MFMA(s16x8 a, s16x8 b, f32x4 c) {
  return __builtin_amdgcn_mfma_f32_16x16x32_bf16(a, b, c, 0, 0, 0);
}
DI s16x8 ldg8(const unsigned short* p) { return *(const s16x8*)p; }

// ---- ws layout (short offsets) ----
#define OFF_WEN   0        // [2048 winT | 8192 wresT] per stack
#define OFF_WAL   10240
#define OFF_WHOW  20480
#define OFF_WHOB  30720
#define OFF_BGEN  40960    // [21][64][32]
#define OFF_BGAL  83968
#define OFF_WIT   126976   // [192][64]
#define OFF_WHT   139264
#define OFF_FC1T  151552   // [64][32]
#define OFF_FC2E  153600   // [16][64] cols:0-5 fc2, 6 how_bout
#define OFF_HOWT  154624   // [64][64]
#define OFF_HOBT  158720   // [16][64] row0 = hob_wout
#define SH_END    159744
// byte offsets
#define B_EMB_EN  (SH_END*2)
#define B_EMB_AL  (B_EMB_EN + 2621440)
#define B_HB      (B_EMB_AL + 2621440)
#define B_GBF     (B_HB + 40960)           // (10240+16) x 64 bf16 (padded)

#define XSTR 40   // x row stride (shorts): 80B -> ~2-way banks on b128
#define HSTR 72   // h row stride (shorts): 144B -> ~2-way banks
#define PSTR 680

// ================= kprep: convert all weights to bf16 MFMA-friendly layouts
__global__ __launch_bounds__(256) void kprep(
    const float* __restrict__ hen_win, const float* __restrict__ hen_wres,
    const float* __restrict__ hal_win, const float* __restrict__ hal_wres,
    const float* __restrict__ how_win, const float* __restrict__ how_wres,
    const float* __restrict__ hob_win, const float* __restrict__ hob_wres,
    const float* __restrict__ hen_wout, const float* __restrict__ hen_bout,
    const float* __restrict__ hal_wout, const float* __restrict__ hal_bout,
    const float* __restrict__ gru_wi, const float* __restrict__ gru_wh,
    const float* __restrict__ fc1_w, const float* __restrict__ fc2_w,
    const float* __restrict__ how_bout, const float* __restrict__ how_wout,
    const float* __restrict__ hob_wout,
    unsigned short* __restrict__ ws)
{
  const int gid = blockIdx.x * 256 + threadIdx.x;
  const int gsz = gridDim.x * 256;
  for (int i = gid; i < 4 * 10240; i += gsz) {
    int s = i / 10240, idx = i - s * 10240;
    const float* win  = (s == 0) ? hen_win  : (s == 1) ? hal_win  : (s == 2) ? how_win  : hob_win;
    const float* wres = (s == 0) ? hen_wres : (s == 1) ? hal_wres : (s == 2) ? how_wres : hob_wres;
    float v;
    if (idx < 2048) { int n = idx >> 5, k = idx & 31; v = (k < 10) ? win[k*64 + n] : 0.f; }
    else { int r = idx - 2048; int d = r >> 12; int r2 = r & 4095; int n = r2 >> 6, k = r2 & 63;
           v = wres[d*4096 + k*64 + n]; }
    ws[s * 10240 + idx] = f2b(v);
  }
  for (int i = gid; i < 2 * 43008; i += gsz) {
    int s = i / 43008, idx = i - s * 43008;
    const float* wout = s ? hal_wout : hen_wout;
    const float* bout = s ? hal_bout : hen_bout;
    int kl = idx & 31, n = (idx >> 5) & 63, c = idx >> 11;
    int kfg = c * 32 + kl;
    float v = 0.f;
    if (kfg < 640)      { int k = kfg / 10, f = kfg - k * 10; v = wout[k*640 + f*64 + n]; }
    else if (kfg < 650) { v = bout[(kfg - 640)*64 + n]; }
    ws[(s ? OFF_BGAL : OFF_BGEN) + idx] = f2b(v);
  }
  for (int i = gid; i < 2 * 12288; i += gsz) {
    int s = i / 12288, idx = i - s * 12288;
    int n = idx >> 6, k = idx & 63;
    const float* w = s ? gru_wh : gru_wi;
    ws[(s ? OFF_WHT : OFF_WIT) + idx] = f2b(w[k*192 + n]);
  }
  for (int i = gid; i < 2048; i += gsz) { int n = i >> 5, k = i & 31; ws[OFF_FC1T + i] = f2b(fc1_w[k*64 + n]); }
  for (int i = gid; i < 1024; i += gsz) {
    int n = i >> 6, k = i & 63;
    float v = 0.f; if (n < 6) v = fc2_w[k*6 + n]; else if (n == 6) v = how_bout[k];
    ws[OFF_FC2E + i] = f2b(v);
  }
  for (int i = gid; i < 4096; i += gsz) ws[OFF_HOWT + i] = f2b(how_wout[i]);
  for (int i = gid; i < 1024; i += gsz) { int n = i >> 6, k = i & 63; ws[OFF_HOBT + i] = f2b(n == 0 ? hob_wout[k] : 0.f); }
}

// ================= barrier-free hypernet stack (wave-local 16-row slabs)
template<int NT>
DI void run_stack(const unsigned short* x_lds, unsigned short* h_lds,
                  const unsigned short* wg, const float* bin, const float* bres,
                  float (&hval)[2][4][4])
{
  const int t = threadIdx.x;
  const int l = t & 63, wv = t >> 6;
  const int lrow = l & 15, lk8 = (l >> 4) * 8, lr4 = (l >> 4) * 4;
  {
    s16x8 bw[4]; float bb0[4];
#pragma unroll
    for (int nt = 0; nt < 4; nt++) { bw[nt] = ldg8(wg + (nt*16 + lrow)*32 + lk8); bb0[nt] = bin[nt*16 + lrow]; }
#pragma unroll
    for (int i = 0; i < 2; i++) {
      int mf = wv + i * 4;
      if (mf < NT) {
        s16x8 a = *(const s16x8*)&x_lds[(mf*16 + lrow)*XSTR + lk8];
#pragma unroll
        for (int nt = 0; nt < 4; nt++) {
          f32x4 d = MFMA(a, bw[nt], f32x4{0.f,0.f,0.f,0.f});
#pragma unroll
          for (int r = 0; r < 4; r++) hval[i][nt][r] = fmaxf(d[r] + bb0[nt], 0.f);
        }
#pragma unroll
        for (int nt = 0; nt < 4; nt++)
#pragma unroll
          for (int r = 0; r < 4; r++)
            h_lds[(mf*16 + lr4 + r)*HSTR + nt*16 + lrow] = f2b(hval[i][nt][r]);
      }
    }
  }
#pragma unroll
  for (int d = 0; d < 2; d++) {
    const unsigned short* wt = wg + 2048 + d * 4096;
    s16x8 bwr[4][2]; float bbr[4];
#pragma unroll
    for (int nt = 0; nt < 4; nt++) {
      bbr[nt] = bres[d*64 + nt*16 + lrow];
      bwr[nt][0] = ldg8(wt + (nt*16 + lrow)*64 + lk8);
      bwr[nt][1] = ldg8(wt + (nt*16 + lrow)*64 + 32 + lk8);
    }
#pragma unroll
    for (int i = 0; i < 2; i++) {
      int mf = wv + i * 4;
      if (mf < NT) {
        s16x8 af0 = *(const s16x8*)&h_lds[(mf*16 + lrow)*HSTR + lk8];
        s16x8 af1 = *(const s16x8*)&h_lds[(mf*16 + lrow)*HSTR + 32 + lk8];
#pragma unroll
        for (int nt = 0; nt < 4; nt++) {
          f32x4 acc = MFMA(af0, bwr[nt][0], f32x4{0.f,0.f,0.f,0.f});
          acc = MFMA(af1, bwr[nt][1], acc);
#pragma unroll
          for (int r = 0; r < 4; r++) hval[i][nt][r] = fmaxf(acc[r] + bbr[nt], 0.f) + hval[i][nt][r];
        }
#pragma unroll
        for (int nt = 0; nt < 4; nt++)
#pragma unroll
          for (int r = 0; r < 4; r++)
            h_lds[(mf*16 + lr4 + r)*HSTR + nt*16 + lrow] = f2b(hval[i][nt][r]);
      }
    }
  }
}

// ================= khyp_ea body: stack + P-build + N-split GEMM -> emb (8 agents/block)
template<int E, int NT>
DI void hyp_body(const float* __restrict__ feats,
                 const unsigned short* __restrict__ Wg, const unsigned short* __restrict__ Bg,
                 const float* __restrict__ bin, const float* __restrict__ bres,
                 float* __restrict__ emb,
                 unsigned short* x_lds, unsigned short* h_lds, unsigned short* P)
{
  const int t = threadIdx.x;
  const int l = t & 63, wv = t >> 6;
  const int lrow = l & 15, lk8 = (l >> 4) * 8, lr4 = (l >> 4) * 4;
  constexpr int MT = E * 8;

  for (int idx = t; idx < 96*32; idx += 256) {
    int row = idx >> 5, c = idx & 31;
    float v = (c < 10 && row < MT) ? feats[row*10 + c] : 0.f;
    x_lds[row*XSTR + c] = f2b(v);
  }
  __syncthreads();

  float hval[2][4][4];
  run_stack<NT>(x_lds, h_lds, Wg, bin, bres, hval);
  __syncthreads();   // h complete across waves (P-build reads all rows)

  // ---- P-build: thread -> (agent a = t>>5, k pair k2, k2+1)
  const int a = t >> 5, k2 = (t & 31) * 2, fx = t & 31;
  float p0[10], p1[10], sxv = 0.f;
#pragma unroll
  for (int f = 0; f < 10; f++) { p0[f] = 0.f; p1[f] = 0.f; }
#pragma unroll
  for (int e = 0; e < E; e++) {
    int row = a * E + e;
    const unsigned short* xr = x_lds + row * XSTR;
    s16x8 xv8 = *(const s16x8*)xr;
    unsigned xv2 = *(const unsigned*)(xr + 8);
    float xf[10];
#pragma unroll
    for (int f = 0; f < 8; f++) xf[f] = b2f((unsigned short)xv8[f]);
    xf[8] = b2f((unsigned short)(xv2 & 0xFFFF));
    xf[9] = b2f((unsigned short)(xv2 >> 16));
    unsigned hp = *(const unsigned*)&h_lds[row*HSTR + k2];
    float h0 = b2f((unsigned short)(hp & 0xFFFF));
    float h1 = b2f((unsigned short)(hp >> 16));
#pragma unroll
    for (int f = 0; f < 10; f++) { p0[f] += h0 * xf[f]; p1[f] += h1 * xf[f]; }
    if (fx < 10) sxv += xf[fx];
  }
  __syncthreads();   // all x/h reads done before P overwrites that LDS
  unsigned* Pw = (unsigned*)(P + a*PSTR + k2*10);
#pragma unroll
  for (int j = 0; j < 5; j++) Pw[j]     = (unsigned)f2b(p0[2*j]) | ((unsigned)f2b(p0[2*j+1]) << 16);
#pragma unroll
  for (int j = 0; j < 5; j++) Pw[5 + j] = (unsigned)f2b(p1[2*j]) | ((unsigned)f2b(p1[2*j+1]) << 16);
  if (fx < 10) P[a*PSTR + 640 + fx] = f2b(sxv);
  __syncthreads();   // P ready

  // ---- GEMM: wave wv owns N-tile wv (16 cols), all 21 chunks; B direct from global
  const int arow = lrow & 7;     // rows 8..15 duplicate agents (discarded)
  const unsigned short* Bw = Bg + (wv*16 + lrow)*32 + lk8;
  f32x4 acc0 = {0.f,0.f,0.f,0.f}, acc1 = {0.f,0.f,0.f,0.f};
  s16x8 aC = *(const s16x8*)&P[arow*PSTR + lk8];
  s16x8 bC = ldg8(Bw);
#pragma unroll
  for (int c = 0; c < 21; c++) {
    s16x8 aN = aC, bN = bC;
    if (c < 20) {
      aN = *(const s16x8*)&P[arow*PSTR + (c+1)*32 + lk8];
      bN = ldg8(Bw + (c+1)*2048);
    }
    if (c & 1) acc1 = MFMA(aC, bC, acc1); else acc0 = MFMA(aC, bC, acc0);
    aC = aN; bC = bN;
  }
  if (l < 32) {
#pragma unroll
    for (int r = 0; r < 4; r++)
      emb[(lr4 + r)*64 + wv*16 + lrow] = acc0[r] + acc1[r];
  }
}

__global__ __launch_bounds__(256) void khyp_ea(
    const float* __restrict__ en_feats, const float* __restrict__ al_feats,
    const unsigned short* __restrict__ ws,
    const float* __restrict__ en_bin, const float* __restrict__ en_bres,
    const float* __restrict__ al_bin, const float* __restrict__ al_bres,
    float* __restrict__ emb_en, float* __restrict__ emb_al)
{
  __shared__ __align__(16) char smem[21504];
  unsigned short* x_lds = (unsigned short*)smem;            // [96][40]
  unsigned short* h_lds = (unsigned short*)(smem + 7680);   // [96][72]
  unsigned short* P     = (unsigned short*)smem;            // [8][680] overlay
  if (blockIdx.x < 1280) {
    int blk = blockIdx.x;
    hyp_body<11,6>(en_feats + blk*880, ws + OFF_WEN, ws + OFF_BGEN,
                   en_bin, en_bres, emb_en + blk*512, x_lds, h_lds, P);
  } else {
    int blk = blockIdx.x - 1280;
    hyp_body<9,5>(al_feats + blk*720, ws + OFF_WAL, ws + OFF_BGAL,
                  al_bin, al_bres, emb_al + blk*512, x_lds, h_lds, P);
  }
}

// ================= kfused: fc1 + embeds + GRU + fc2/hb + g  (all MFMA, 16 agents/block)
__global__ __launch_bounds__(256) void kfused(
    const float* __restrict__ own, const float* __restrict__ agent_emb,
    const float* __restrict__ action_emb,
    const int* __restrict__ agent_idx, const int* __restrict__ last_action,
    const float* __restrict__ emb_en, const float* __restrict__ emb_al,
    const float* __restrict__ hidden,
    const unsigned short* __restrict__ ws,
    const float* __restrict__ fc1_b, const float* __restrict__ bi,
    const float* __restrict__ bh, const float* __restrict__ fc2_b,
    float* __restrict__ qout, float* __restrict__ hhout,
    unsigned short* __restrict__ g_bf, float* __restrict__ hb)
{
  __shared__ unsigned short own_lds[16*32];
  __shared__ unsigned short x_lds[16*HSTR];
  __shared__ unsigned short hp_lds[16*HSTR];
  __shared__ unsigned short hh_lds[16*HSTR];
  const int t = threadIdx.x;
  const int l = t & 63, wv = t >> 6;
  const int lrow = l & 15, lk8 = (l >> 4) * 8, lr4 = (l >> 4) * 4;
  const int n0 = blockIdx.x * 16;

  const unsigned short* fc1T = ws + OFF_FC1T;
  const unsigned short* wiT  = ws + OFF_WIT;
  const unsigned short* whT  = ws + OFF_WHT;
  const unsigned short* howT = ws + OFF_HOWT;
  const unsigned short* fc2e = ws + OFF_FC2E;

  for (int i = t; i < 512; i += 256) own_lds[i] = f2b(own[n0*32 + i]);
  for (int i = t; i < 1024; i += 256) hp_lds[(i >> 6)*HSTR + (i & 63)] = f2b(hidden[n0*64 + i]);
  __syncthreads();

  const int j = wv * 16 + lrow;
  {  // fc1 + gathers -> x
    s16x8 a0 = *(const s16x8*)&own_lds[lrow*32 + lk8];
    s16x8 b0 = ldg8(fc1T + (wv*16 + lrow)*32 + lk8);
    f32x4 c0 = MFMA(a0, b0, f32x4{0.f,0.f,0.f,0.f});
    float fb = fc1_b[j];
#pragma unroll
    for (int r = 0; r < 4; r++) {
      int aa = lr4 + r; int n = n0 + aa;
      int ai = agent_idx[n], la = last_action[n];
      float v = c0[r] + fb + agent_emb[ai*64 + j] + action_emb[la*64 + j]
              + emb_en[n*64 + j] + emb_al[n*64 + j];
      x_lds[aa*HSTR + j] = f2b(fmaxf(v, 0.f));
    }
  }
  __syncthreads();

  {  // GRU
    s16x8 xa[2], ha[2];
#pragma unroll
    for (int s = 0; s < 2; s++) {
      xa[s] = *(const s16x8*)&x_lds[lrow*HSTR + s*32 + lk8];
      ha[s] = *(const s16x8*)&hp_lds[lrow*HSTR + s*32 + lk8];
    }
    f32x4 gi[3], gh[3];
#pragma unroll
    for (int g3 = 0; g3 < 3; g3++) { gi[g3] = f32x4{0.f,0.f,0.f,0.f}; gh[g3] = f32x4{0.f,0.f,0.f,0.f}; }
#pragma unroll
    for (int g3 = 0; g3 < 3; g3++) {
      int tl = wv + g3 * 4;
#pragma unroll
      for (int s = 0; s < 2; s++) {
        gi[g3] = MFMA(xa[s], ldg8(wiT + (tl*16 + lrow)*64 + s*32 + lk8), gi[g3]);
        gh[g3] = MFMA(ha[s], ldg8(whT + (tl*16 + lrow)*64 + s*32 + lk8), gh[g3]);
      }
    }
    float bir = bi[j], biz = bi[64 + j], bin_ = bi[128 + j];
    float bhr = bh[j], bhz = bh[64 + j], bhn = bh[128 + j];
#pragma unroll
    for (int r = 0; r < 4; r++) {
      int aa = lr4 + r; int n = n0 + aa;
      float rr = 1.f / (1.f + __expf(-(gi[0][r] + bir + gh[0][r] + bhr)));
      float zz = 1.f / (1.f + __expf(-(gi[1][r] + biz + gh[1][r] + bhz)));
      float nn = tanhf(gi[2][r] + bin_ + rr * (gh[2][r] + bhn));
      float hp = hidden[n*64 + j];
      float hhv = (1.f - zz) * nn + zz * hp;
      hhout[n*64 + j] = hhv;
      hh_lds[aa*HSTR + j] = f2b(hhv);
    }
  }
  __syncthreads();

  {  // g = hh @ howT ; fc2ext (q_normal + hb)
    s16x8 hha[2];
#pragma unroll
    for (int s = 0; s < 2; s++) hha[s] = *(const s16x8*)&hh_lds[lrow*HSTR + s*32 + lk8];
    f32x4 gc = {0.f,0.f,0.f,0.f};
#pragma unroll
    for (int s = 0; s < 2; s++) gc = MFMA(hha[s], ldg8(howT + (wv*16 + lrow)*64 + s*32 + lk8), gc);
#pragma unroll
    for (int r = 0; r < 4; r++) g_bf[(n0 + lr4 + r)*64 + wv*16 + lrow] = f2b(gc[r]);
    if (wv == 0) {
      f32x4 qc = {0.f,0.f,0.f,0.f};
#pragma unroll
      for (int s = 0; s < 2; s++) qc = MFMA(hha[s], ldg8(fc2e + lrow*64 + s*32 + lk8), qc);
#pragma unroll
      for (int r = 0; r < 4; r++) {
        int n = n0 + lr4 + r;
        if (lrow < 6)       qout[n*17 + lrow] = qc[r] + fc2_b[lrow];
        else if (lrow == 6) hb[n] = qc[r];
      }
    }
  }
}

// ================= kattack: hob stack -> qB(regs); how stack -> q_attack (8 agents/block)
__global__ __launch_bounds__(256) void kattack(
    const float* __restrict__ en_feats, const unsigned short* __restrict__ ws,
    const float* __restrict__ how_bin, const float* __restrict__ how_bres,
    const float* __restrict__ hob_bin, const float* __restrict__ hob_bres,
    const unsigned short* __restrict__ g_bf, const float* __restrict__ hb,
    const float* __restrict__ hob_bout, float* __restrict__ qout)
{
  __shared__ __align__(16) char smem[21504];
  unsigned short* x_lds = (unsigned short*)smem;            // [96][40]
  unsigned short* h_lds = (unsigned short*)(smem + 7680);   // [96][72]
  const int t = threadIdx.x;
  const int l = t & 63, wv = t >> 6;
  const int lrow = l & 15, lk8 = (l >> 4) * 8, lr4 = (l >> 4) * 4;
  const int blk = blockIdx.x;
  const float* feats = en_feats + blk * 880;

  for (int idx = t; idx < 96*32; idx += 256) {
    int row = idx >> 5, c = idx & 31;
    float v = (c < 10 && row < 88) ? feats[row*10 + c] : 0.f;
    x_lds[row*XSTR + c] = f2b(v);
  }
  __syncthreads();   // the ONLY barrier

  float hval[2][4][4];
  run_stack<6>(x_lds, h_lds, ws + OFF_WHOB, hob_bin, hob_bres, hval);
  float qb[2][4];
#pragma unroll
  for (int i = 0; i < 2; i++) {
    int mf = wv + i * 4;
    if (mf < 6) {
      s16x8 a0 = *(const s16x8*)&h_lds[(mf*16 + lrow)*HSTR + lk8];
      s16x8 a1 = *(const s16x8*)&h_lds[(mf*16 + lrow)*HSTR + 32 + lk8];
      f32x4 qc = MFMA(a0, ldg8(ws + OFF_HOBT + lrow*64 + lk8), f32x4{0.f,0.f,0.f,0.f});
      qc = MFMA(a1, ldg8(ws + OFF_HOBT + lrow*64 + 32 + lk8), qc);
#pragma unroll
      for (int r = 0; r < 4; r++) qb[i][r] = qc[r];   // col value; col0 (lrow==0) is qB
    }
  }
  run_stack<6>(x_lds, h_lds, ws + OFF_WHOW, how_bin, how_bres, hval);

  float hob_b0 = hob_bout[0];
#pragma unroll
  for (int i = 0; i < 2; i++) {
    int mf = wv + i * 4;
    if (mf < 6) {
      s16x8 a0 = *(const s16x8*)&h_lds[(mf*16 + lrow)*HSTR + lk8];
      s16x8 a1 = *(const s16x8*)&h_lds[(mf*16 + lrow)*HSTR + 32 + lk8];
      f32x4 qc = MFMA(a0, ldg8(g_bf + ((long)blk*8 + lrow)*64 + lk8), f32x4{0.f,0.f,0.f,0.f});
      qc = MFMA(a1, ldg8(g_bf + ((long)blk*8 + lrow)*64 + 32 + lk8), qc);
#pragma unroll
      for (int r = 0; r < 4; r++) {
        int row = mf*16 + lr4 + r;
        int ag = row / 11;
        float qBv = __shfl(qb[i][r], l & 48, 64);   // broadcast col-0 lane
        if (row < 88 && ag == lrow) {
          int n = blk*8 + ag;
          qout[n*17 + 6 + (row - ag*11)] = qc[r] + qBv + hb[n] + hob_b0;
        }
      }
    }
  }
}

extern "C" void kernel_launch(void* const* d_in, const int* in_sizes, int n_in,
                              void* d_out, int out_size, void* d_ws, size_t ws_size,
                              hipStream_t stream)
{
  (void)in_sizes; (void)n_in; (void)out_size; (void)ws_size;
  const float* own        = (const float*)d_in[0];
  const float* enemy      = (const float*)d_in[1];
  const float* ally       = (const float*)d_in[2];
  const float* hidden     = (const float*)d_in[3];
  const float* fc1_w      = (const float*)d_in[4];
  const float* fc1_b      = (const float*)d_in[5];
  const float* agent_emb  = (const float*)d_in[6];
  const float* action_emb = (const float*)d_in[7];
  const float* hen_win  = (const float*)d_in[8];  const float* hen_bin  = (const float*)d_in[9];
  const float* hen_wres = (const float*)d_in[10]; const float* hen_bres = (const float*)d_in[11];
  const float* hen_wout = (const float*)d_in[12]; const float* hen_bout = (const float*)d_in[13];
  const float* hal_win  = (const float*)d_in[14]; const float* hal_bin  = (const float*)d_in[15];
  const float* hal_wres = (const float*)d_in[16]; const float* hal_bres = (const float*)d_in[17];
  const float* hal_wout = (const float*)d_in[18]; const float* hal_bout = (const float*)d_in[19];
  const float* gru_wi = (const float*)d_in[20];   const float* gru_wh = (const float*)d_in[21];
  const float* gru_bi = (const float*)d_in[22];   const float* gru_bh = (const float*)d_in[23];
  const float* fc2_w  = (const float*)d_in[24];   const float* fc2_b  = (const float*)d_in[25];
  const float* how_win  = (const float*)d_in[26]; const float* how_bin  = (const float*)d_in[27];
  const float* how_wres = (const float*)d_in[28]; const float* how_bres = (const float*)d_in[29];
  const float* how_wout = (const float*)d_in[30]; const float* how_bout = (const float*)d_in[31];
  const float* hob_win  = (const float*)d_in[32]; const float* hob_bin  = (const float*)d_in[33];
  const float* hob_wres = (const float*)d_in[34]; const float* hob_bres = (const float*)d_in[35];
  const float* hob_wout = (const float*)d_in[36]; const float* hob_bout = (const float*)d_in[37];
  const int* agent_idx   = (const int*)d_in[38];
  const int* last_action = (const int*)d_in[39];

  unsigned short* ws = (unsigned short*)d_ws;
  float* emb_en = (float*)((char*)d_ws + B_EMB_EN);
  float* emb_al = (float*)((char*)d_ws + B_EMB_AL);
  float* hb     = (float*)((char*)d_ws + B_HB);
  unsigned short* g_bf = (unsigned short*)((char*)d_ws + B_GBF);

  float* q  = (float*)d_out;
  float* hh = q + 1024*10*17;

  kprep<<<128, 256, 0, stream>>>(hen_win, hen_wres, hal_win, hal_wres,
      how_win, how_wres, hob_win, hob_wres,
      hen_wout, hen_bout, hal_wout, hal_bout,
      gru_wi, gru_wh, fc1_w, fc2_w, how_bout, how_wout, hob_wout, ws);
  khyp_ea<<<2560, 256, 0, stream>>>(enemy, ally, ws,
      hen_bin, hen_bres, hal_bin, hal_bres, emb_en, emb_al);
  kfused<<<640, 256, 0, stream>>>(own, agent_emb, action_emb, agent_idx, last_action,
      emb_en, emb_al, hidden, ws, fc1_b, gru_bi, gru_bh, fc2_b, q, hh, g_bf, hb);
  kattack<<<1280, 256, 0, stream>>>(enemy, ws, how_bin, how_bres, hob_bin, hob_bres,
      g_bf, hb, hob_bout, q);
}

// Round 5
// 78.494 us; speedup vs baseline: 2.0909x; 1.3549x over previous
//
#include <hip/hip_runtime.h>

#define DI static __device__ __forceinline__

typedef short s16x8 __attribute__((ext_vector_type(8)));
typedef float f32x4 __attribute__((ext_vector_type(4)));
typedef float f32x2 __attribute__((ext_vector_type(2)));
typedef unsigned u32x2 __attribute__((ext_vector_type(2)));

DI unsigned short f2b(float f) {
  union { float f; unsigned u; } v; v.f = f;
  return (unsigned short)((v.u + 0x7FFF + ((v.u >> 16) & 1)) >> 16);  // RNE
}
DI float b2f(unsigned short s) {
  union { unsigned u; float f; } v; v.u = ((unsigned)s) << 16;
  return v.f;
}
DI unsigned cvtpk(float lo, float hi) {
  unsigned r;
  asm("v_cvt_pk_bf16_f32 %0, %1, %2" : "=v"(r) : "v"(lo), "v"(hi));
  return r;
}
DI f32x4 MFMA(s16x8 a, s16x8 b, f32x4 c) {
  return __builtin_amdgcn_mfma_f32_16x16x32_bf16(a, b, c, 0, 0, 0);
}
DI s16x8 ldg8(const unsigned short* p) { return *(const s16x8*)p; }

// ---- ws layout (short offsets) ----
#define OFF_WEN   0        // [2048 winT | 8192 wresT] per stack (= W^T, A-operand layout)
#define OFF_WAL   10240
#define OFF_WHOW  20480
#define OFF_WHOB  30720
#define OFF_BGEN  40960    // [21][64][32]
#define OFF_BGAL  83968
#define OFF_WIT   126976   // [192][64]
#define OFF_WHT   139264
#define OFF_FC1T  151552   // [64][32]
#define OFF_FC2E  153600   // [16][64] cols:0-5 fc2, 6 how_bout
#define OFF_HOWT  154624   // [64][64]
#define OFF_HOBT  158720   // unused now (kept for layout stability)
#define SH_END    159744
// byte offsets
#define B_EMB_EN  (SH_END*2)
#define B_EMB_AL  (B_EMB_EN + 2621440)
#define B_HB      (B_EMB_AL + 2621440)
#define B_GBF     (B_HB + 40960)

#define XSTR 40
#define HSTR 72
#define PSTR 680

// ================= kprep (unchanged layouts) =================
__global__ __launch_bounds__(256) void kprep(
    const float* __restrict__ hen_win, const float* __restrict__ hen_wres,
    const float* __restrict__ hal_win, const float* __restrict__ hal_wres,
    const float* __restrict__ how_win, const float* __restrict__ how_wres,
    const float* __restrict__ hob_win, const float* __restrict__ hob_wres,
    const float* __restrict__ hen_wout, const float* __restrict__ hen_bout,
    const float* __restrict__ hal_wout, const float* __restrict__ hal_bout,
    const float* __restrict__ gru_wi, const float* __restrict__ gru_wh,
    const float* __restrict__ fc1_w, const float* __restrict__ fc2_w,
    const float* __restrict__ how_bout, const float* __restrict__ how_wout,
    const float* __restrict__ hob_wout,
    unsigned short* __restrict__ ws)
{
  const int gid = blockIdx.x * 256 + threadIdx.x;
  const int gsz = gridDim.x * 256;
  for (int i = gid; i < 4 * 10240; i += gsz) {
    int s = i / 10240, idx = i - s * 10240;
    const float* win  = (s == 0) ? hen_win  : (s == 1) ? hal_win  : (s == 2) ? how_win  : hob_win;
    const float* wres = (s == 0) ? hen_wres : (s == 1) ? hal_wres : (s == 2) ? how_wres : hob_wres;
    float v;
    if (idx < 2048) { int n = idx >> 5, k = idx & 31; v = (k < 10) ? win[k*64 + n] : 0.f; }
    else { int r = idx - 2048; int d = r >> 12; int r2 = r & 4095; int n = r2 >> 6, k = r2 & 63;
           v = wres[d*4096 + k*64 + n]; }
    ws[s * 10240 + idx] = f2b(v);
  }
  for (int i = gid; i < 2 * 43008; i += gsz) {
    int s = i / 43008, idx = i - s * 43008;
    const float* wout = s ? hal_wout : hen_wout;
    const float* bout = s ? hal_bout : hen_bout;
    int kl = idx & 31, n = (idx >> 5) & 63, c = idx >> 11;
    int kfg = c * 32 + kl;
    float v = 0.f;
    if (kfg < 640)      { int k = kfg / 10, f = kfg - k * 10; v = wout[k*640 + f*64 + n]; }
    else if (kfg < 650) { v = bout[(kfg - 640)*64 + n]; }
    ws[(s ? OFF_BGAL : OFF_BGEN) + idx] = f2b(v);
  }
  for (int i = gid; i < 2 * 12288; i += gsz) {
    int s = i / 12288, idx = i - s * 12288;
    int n = idx >> 6, k = idx & 63;
    const float* w = s ? gru_wh : gru_wi;
    ws[(s ? OFF_WHT : OFF_WIT) + idx] = f2b(w[k*192 + n]);
  }
  for (int i = gid; i < 2048; i += gsz) { int n = i >> 5, k = i & 31; ws[OFF_FC1T + i] = f2b(fc1_w[k*64 + n]); }
  for (int i = gid; i < 1024; i += gsz) {
    int n = i >> 6, k = i & 63;
    float v = 0.f; if (n < 6) v = fc2_w[k*6 + n]; else if (n == 6) v = how_bout[k];
    ws[OFF_FC2E + i] = f2b(v);
  }
  for (int i = gid; i < 4096; i += gsz) ws[OFF_HOWT + i] = f2b(how_wout[i]);
}

// ================= stack_batch: h^T = W^T x^T ; up to TMAX tiles per wave, layer-major.
// Weights are the A-operand (frags straight from global ws). x/h are B-operands.
// D layout: row-field = neuron (gq*4+r, +16*mt), col-field = batch row (l&15).
// h round-trips through wave-private LDS rows as packed b64 writes + b128 reads.
template<int TMAX, bool WLAST>
DI void stack_batch(const unsigned short* __restrict__ x_lds,
                    unsigned short* const (&hbp)[TMAX], const int (&tis)[TMAX], int E,
                    const unsigned short* __restrict__ wg,
                    const float* __restrict__ bin, const float* __restrict__ bres,
                    f32x4 (&hval)[TMAX][4])
{
  const int l = threadIdx.x & 63;
  const int lrow = l & 15, gq = l >> 4, lk8 = gq * 8;
  // ---- layer 1 (K=32)
  {
    s16x8 wf[4]; f32x4 bv[4];
#pragma unroll
    for (int mt = 0; mt < 4; mt++) {
      wf[mt] = ldg8(wg + (mt*16 + lrow)*32 + lk8);
      bv[mt] = *(const f32x4*)(bin + mt*16 + gq*4);
    }
#pragma unroll
    for (int tt = 0; tt < TMAX; tt++) {
      if (tis[tt] < E) {
        s16x8 xf = *(const s16x8*)&x_lds[(tis[tt]*16 + lrow)*XSTR + lk8];
#pragma unroll
        for (int mt = 0; mt < 4; mt++) {
          f32x4 d = MFMA(wf[mt], xf, f32x4{0.f,0.f,0.f,0.f});
#pragma unroll
          for (int r = 0; r < 4; r++) hval[tt][mt][r] = fmaxf(d[r] + bv[mt][r], 0.f);
        }
        unsigned short* wr = hbp[tt] + lrow*HSTR;
#pragma unroll
        for (int mt = 0; mt < 4; mt++) {
          u32x2 pw;
          pw.x = cvtpk(hval[tt][mt][0], hval[tt][mt][1]);
          pw.y = cvtpk(hval[tt][mt][2], hval[tt][mt][3]);
          *(u32x2*)&wr[mt*16 + gq*4] = pw;
        }
      }
    }
  }
  // ---- 2 residual layers (K=64)
#pragma unroll
  for (int d = 0; d < 2; d++) {
    const unsigned short* wt = wg + 2048 + d * 4096;
    s16x8 wf[4][2]; f32x4 bv[4];
#pragma unroll
    for (int mt = 0; mt < 4; mt++) {
      wf[mt][0] = ldg8(wt + (mt*16 + lrow)*64 + lk8);
      wf[mt][1] = ldg8(wt + (mt*16 + lrow)*64 + 32 + lk8);
      bv[mt] = *(const f32x4*)(bres + d*64 + mt*16 + gq*4);
    }
#pragma unroll
    for (int tt = 0; tt < TMAX; tt++) {
      if (tis[tt] < E) {
        const unsigned short* hr = hbp[tt] + lrow*HSTR;
        s16x8 b0 = *(const s16x8*)&hr[lk8];
        s16x8 b1 = *(const s16x8*)&hr[32 + lk8];
#pragma unroll
        for (int mt = 0; mt < 4; mt++) {
          f32x4 a = MFMA(wf[mt][0], b0, f32x4{0.f,0.f,0.f,0.f});
          a = MFMA(wf[mt][1], b1, a);
#pragma unroll
          for (int r = 0; r < 4; r++)
            hval[tt][mt][r] = fmaxf(a[r] + bv[mt][r], 0.f) + hval[tt][mt][r];
        }
        if (d == 0 || WLAST) {
          unsigned short* wr = hbp[tt] + lrow*HSTR;
#pragma unroll
          for (int mt = 0; mt < 4; mt++) {
            u32x2 pw;
            pw.x = cvtpk(hval[tt][mt][0], hval[tt][mt][1]);
            pw.y = cvtpk(hval[tt][mt][2], hval[tt][mt][3]);
            *(u32x2*)&wr[mt*16 + gq*4] = pw;
          }
        }
      }
    }
  }
}

// ================= khyp body: 16 agents/block, E tiles =================
template<int E>
DI void hyp_body16(const float* __restrict__ feats,
                   const unsigned short* __restrict__ Wg, const unsigned short* __restrict__ Bg,
                   const float* __restrict__ bin, const float* __restrict__ bres,
                   float* __restrict__ emb, char* smem)
{
  unsigned short* x_lds = (unsigned short*)smem;            // [16E][40]
  unsigned short* h_lds = (unsigned short*)(smem + 14080);  // [16E][72]
  unsigned short* P     = (unsigned short*)smem;            // [16][680] overlay (post-barrier)
  const int t = threadIdx.x;
  const int l = t & 63, wv = t >> 6;
  const int lrow = l & 15, gq = l >> 4, lk8 = gq * 8, lr4 = gq * 4;

  for (int idx = t; idx < E * 512; idx += 256) {
    int row = idx >> 5, c = idx & 31;
    x_lds[row*XSTR + c] = (c < 10) ? f2b(feats[row*10 + c]) : (unsigned short)0;
  }
  __syncthreads();

  int tis[3] = {wv, wv + 4, wv + 8};
  unsigned short* hbp[3] = { h_lds + (wv)*16*HSTR, h_lds + (wv+4)*16*HSTR, h_lds + (wv+8)*16*HSTR };
  f32x4 hval[3][4];
  stack_batch<3, true>(x_lds, hbp, tis, E, Wg, bin, bres, hval);
  __syncthreads();   // h complete across waves

  // ---- P-build: thread = (agent a, k-quad kq)
  const int a = t >> 4, kq = t & 15, k0 = kq * 4;
  float acc[4][10];
#pragma unroll
  for (int kk = 0; kk < 4; kk++)
#pragma unroll
    for (int f = 0; f < 10; f++) acc[kk][f] = 0.f;
#pragma unroll
  for (int e = 0; e < E; e++) {
    int row = a * E + e;
    const unsigned short* xr = x_lds + row * XSTR;
    s16x8 xv8 = *(const s16x8*)xr;
    unsigned xv2 = *(const unsigned*)(xr + 8);
    float xf[10];
#pragma unroll
    for (int f = 0; f < 8; f++) xf[f] = b2f((unsigned short)xv8[f]);
    xf[8] = b2f((unsigned short)(xv2 & 0xFFFF));
    xf[9] = b2f((unsigned short)(xv2 >> 16));
    u32x2 hp = *(const u32x2*)&h_lds[row*HSTR + k0];
    float hf[4] = { b2f((unsigned short)(hp.x & 0xFFFF)), b2f((unsigned short)(hp.x >> 16)),
                    b2f((unsigned short)(hp.y & 0xFFFF)), b2f((unsigned short)(hp.y >> 16)) };
#pragma unroll
    for (int kk = 0; kk < 4; kk++)
#pragma unroll
      for (int f = 0; f < 10; f++) acc[kk][f] += hf[kk] * xf[f];
  }
  float sxv = 0.f; int a2 = 0, fx = 0;
  if (t < 160) {
    a2 = t / 10; fx = t - a2 * 10;
    for (int e = 0; e < E; e++) sxv += feats[(a2*E + e)*10 + fx];
  }
  __syncthreads();   // all x/h reads done; P may overlay

  u32x2* Pw = (u32x2*)(P + a*PSTR + k0*10);
#pragma unroll
  for (int m = 0; m < 10; m++) {
    const int s0 = 4*m, s1 = 4*m+1, s2 = 4*m+2, s3 = 4*m+3;
    u32x2 pw;
    pw.x = cvtpk(acc[s0/10][s0%10], acc[s1/10][s1%10]);
    pw.y = cvtpk(acc[s2/10][s2%10], acc[s3/10][s3%10]);
    Pw[m] = pw;
  }
  if (t < 160) P[a2*PSTR + 640 + fx] = f2b(sxv);
  for (int i = t; i < 352; i += 256) { int a3 = i / 22, c = i - a3*22; P[a3*PSTR + 650 + c] = 0; }
  __syncthreads();   // P ready

  // ---- GEMM: wave wv owns n-tile wv; M = 16 agents (full); B direct from global
  f32x4 acc0 = {0.f,0.f,0.f,0.f}, acc1 = {0.f,0.f,0.f,0.f};
  const unsigned short* Bw = Bg + (wv*16 + lrow)*32 + lk8;
#pragma unroll
  for (int c = 0; c < 21; c++) {
    s16x8 af = *(const s16x8*)&P[lrow*PSTR + c*32 + lk8];
    s16x8 bf = ldg8(Bw + c*2048);
    if (c & 1) acc1 = MFMA(af, bf, acc1); else acc0 = MFMA(af, bf, acc0);
  }
#pragma unroll
  for (int r = 0; r < 4; r++)
    emb[(lr4 + r)*64 + wv*16 + lrow] = acc0[r] + acc1[r];
}

__global__ __launch_bounds__(256) void khyp_ea(
    const float* __restrict__ en_feats, const float* __restrict__ al_feats,
    const unsigned short* __restrict__ ws,
    const float* __restrict__ en_bin, const float* __restrict__ en_bres,
    const float* __restrict__ al_bin, const float* __restrict__ al_bres,
    float* __restrict__ emb_en, float* __restrict__ emb_al)
{
  __shared__ __align__(16) char smem[39424];
  if (blockIdx.x < 640) {
    int blk = blockIdx.x;
    hyp_body16<11>(en_feats + (long)blk*1760, ws + OFF_WEN, ws + OFF_BGEN,
                   en_bin, en_bres, emb_en + (long)blk*1024, smem);
  } else {
    int blk = blockIdx.x - 640;
    hyp_body16<9>(al_feats + (long)blk*1440, ws + OFF_WAL, ws + OFF_BGAL,
                  al_bin, al_bres, emb_al + (long)blk*1024, smem);
  }
}

// ================= kfused (unchanged from R4) =================
__global__ __launch_bounds__(256) void kfused(
    const float* __restrict__ own, const float* __restrict__ agent_emb,
    const float* __restrict__ action_emb,
    const int* __restrict__ agent_idx, const int* __restrict__ last_action,
    const float* __restrict__ emb_en, const float* __restrict__ emb_al,
    const float* __restrict__ hidden,
    const unsigned short* __restrict__ ws,
    const float* __restrict__ fc1_b, const float* __restrict__ bi,
    const float* __restrict__ bh, const float* __restrict__ fc2_b,
    float* __restrict__ qout, float* __restrict__ hhout,
    unsigned short* __restrict__ g_bf, float* __restrict__ hb)
{
  __shared__ unsigned short own_lds[16*32];
  __shared__ unsigned short x_lds[16*HSTR];
  __shared__ unsigned short hp_lds[16*HSTR];
  __shared__ unsigned short hh_lds[16*HSTR];
  const int t = threadIdx.x;
  const int l = t & 63, wv = t >> 6;
  const int lrow = l & 15, lk8 = (l >> 4) * 8, lr4 = (l >> 4) * 4;
  const int n0 = blockIdx.x * 16;

  const unsigned short* fc1T = ws + OFF_FC1T;
  const unsigned short* wiT  = ws + OFF_WIT;
  const unsigned short* whT  = ws + OFF_WHT;
  const unsigned short* howT = ws + OFF_HOWT;
  const unsigned short* fc2e = ws + OFF_FC2E;

  for (int i = t; i < 512; i += 256) own_lds[i] = f2b(own[n0*32 + i]);
  for (int i = t; i < 1024; i += 256) hp_lds[(i >> 6)*HSTR + (i & 63)] = f2b(hidden[n0*64 + i]);
  __syncthreads();

  const int j = wv * 16 + lrow;
  {
    s16x8 a0 = *(const s16x8*)&own_lds[lrow*32 + lk8];
    s16x8 b0 = ldg8(fc1T + (wv*16 + lrow)*32 + lk8);
    f32x4 c0 = MFMA(a0, b0, f32x4{0.f,0.f,0.f,0.f});
    float fb = fc1_b[j];
#pragma unroll
    for (int r = 0; r < 4; r++) {
      int aa = lr4 + r; int n = n0 + aa;
      int ai = agent_idx[n], la = last_action[n];
      float v = c0[r] + fb + agent_emb[ai*64 + j] + action_emb[la*64 + j]
              + emb_en[n*64 + j] + emb_al[n*64 + j];
      x_lds[aa*HSTR + j] = f2b(fmaxf(v, 0.f));
    }
  }
  __syncthreads();

  {
    s16x8 xa[2], ha[2];
#pragma unroll
    for (int s = 0; s < 2; s++) {
      xa[s] = *(const s16x8*)&x_lds[lrow*HSTR + s*32 + lk8];
      ha[s] = *(const s16x8*)&hp_lds[lrow*HSTR + s*32 + lk8];
    }
    f32x4 gi[3], gh[3];
#pragma unroll
    for (int g3 = 0; g3 < 3; g3++) { gi[g3] = f32x4{0.f,0.f,0.f,0.f}; gh[g3] = f32x4{0.f,0.f,0.f,0.f}; }
#pragma unroll
    for (int g3 = 0; g3 < 3; g3++) {
      int tl = wv + g3 * 4;
#pragma unroll
      for (int s = 0; s < 2; s++) {
        gi[g3] = MFMA(xa[s], ldg8(wiT + (tl*16 + lrow)*64 + s*32 + lk8), gi[g3]);
        gh[g3] = MFMA(ha[s], ldg8(whT + (tl*16 + lrow)*64 + s*32 + lk8), gh[g3]);
      }
    }
    float bir = bi[j], biz = bi[64 + j], bin_ = bi[128 + j];
    float bhr = bh[j], bhz = bh[64 + j], bhn = bh[128 + j];
#pragma unroll
    for (int r = 0; r < 4; r++) {
      int aa = lr4 + r; int n = n0 + aa;
      float rr = 1.f / (1.f + __expf(-(gi[0][r] + bir + gh[0][r] + bhr)));
      float zz = 1.f / (1.f + __expf(-(gi[1][r] + biz + gh[1][r] + bhz)));
      float nn = tanhf(gi[2][r] + bin_ + rr * (gh[2][r] + bhn));
      float hp = hidden[n*64 + j];
      float hhv = (1.f - zz) * nn + zz * hp;
      hhout[n*64 + j] = hhv;
      hh_lds[aa*HSTR + j] = f2b(hhv);
    }
  }
  __syncthreads();

  {
    s16x8 hha[2];
#pragma unroll
    for (int s = 0; s < 2; s++) hha[s] = *(const s16x8*)&hh_lds[lrow*HSTR + s*32 + lk8];
    f32x4 gc = {0.f,0.f,0.f,0.f};
#pragma unroll
    for (int s = 0; s < 2; s++) gc = MFMA(hha[s], ldg8(howT + (wv*16 + lrow)*64 + s*32 + lk8), gc);
#pragma unroll
    for (int r = 0; r < 4; r++) g_bf[(n0 + lr4 + r)*64 + wv*16 + lrow] = f2b(gc[r]);
    if (wv == 0) {
      f32x4 qc = {0.f,0.f,0.f,0.f};
#pragma unroll
      for (int s = 0; s < 2; s++) qc = MFMA(hha[s], ldg8(fc2e + lrow*64 + s*32 + lk8), qc);
#pragma unroll
      for (int r = 0; r < 4; r++) {
        int n = n0 + lr4 + r;
        if (lrow < 6)       qout[n*17 + lrow] = qc[r] + fc2_b[lrow];
        else if (lrow == 6) hb[n] = qc[r];
      }
    }
  }
}

// ================= kattack: 16 agents/block; both stacks in registers; in-reg epilogue dots
__global__ __launch_bounds__(256) void kattack(
    const float* __restrict__ en_feats, const unsigned short* __restrict__ ws,
    const float* __restrict__ how_bin, const float* __restrict__ how_bres,
    const float* __restrict__ hob_bin, const float* __restrict__ hob_bres,
    const unsigned short* __restrict__ g_bf, const float* __restrict__ hbuf,
    const float* __restrict__ hob_wout, const float* __restrict__ hob_bout,
    float* __restrict__ qout)
{
  __shared__ __align__(16) char smem[41728];   // x 14080 + 12 scratch slots * 2304
  unsigned short* x_lds = (unsigned short*)smem;
  unsigned short* scr   = (unsigned short*)(smem + 14080);
  const int t = threadIdx.x;
  const int l = t & 63, wv = t >> 6;
  const int lrow = l & 15, gq = l >> 4;
  const int blk = blockIdx.x;
  const float* feats = en_feats + (long)blk * 1760;

  for (int idx = t; idx < 176*32; idx += 256) {
    int row = idx >> 5, c = idx & 31;
    x_lds[row*XSTR + c] = (c < 10) ? f2b(feats[row*10 + c]) : (unsigned short)0;
  }
  __syncthreads();   // the only barrier

  int tis[3] = {wv, wv + 4, wv + 8};
  unsigned short* hbp[3] = { scr + (wv*3+0)*16*HSTR, scr + (wv*3+1)*16*HSTR, scr + (wv*3+2)*16*HSTR };
  f32x4 hval[3][4];

  // ---- hob stack -> qB (from f32 regs)
  stack_batch<3, false>(x_lds, hbp, tis, 11, ws + OFF_WHOB, hob_bin, hob_bres, hval);
  f32x4 hw[4];
#pragma unroll
  for (int mt = 0; mt < 4; mt++) hw[mt] = *(const f32x4*)(hob_wout + mt*16 + gq*4);
  float qbv[3] = {0.f, 0.f, 0.f};
#pragma unroll
  for (int tt = 0; tt < 3; tt++) {
    if (tis[tt] < 11) {
      float s = 0.f;
#pragma unroll
      for (int mt = 0; mt < 4; mt++)
#pragma unroll
        for (int r = 0; r < 4; r++) s += hval[tt][mt][r] * hw[mt][r];
      s += __shfl_xor(s, 16, 64);
      s += __shfl_xor(s, 32, 64);
      qbv[tt] = s;
    }
  }

  // ---- how stack -> q_attack
  stack_batch<3, false>(x_lds, hbp, tis, 11, ws + OFF_WHOW, how_bin, how_bres, hval);
  const float hob_b0 = hob_bout[0];
#pragma unroll
  for (int tt = 0; tt < 3; tt++) {
    if (tis[tt] < 11) {
      int row = tis[tt]*16 + lrow;
      int ag = (unsigned)row / 11u;
      int n = blk*16 + ag;
      float s = 0.f;
#pragma unroll
      for (int mt = 0; mt < 4; mt++) {
        u32x2 gv = *(const u32x2*)(g_bf + (long)n*64 + mt*16 + gq*4);
        s += hval[tt][mt][0] * b2f((unsigned short)(gv.x & 0xFFFF))
           + hval[tt][mt][1] * b2f((unsigned short)(gv.x >> 16))
           + hval[tt][mt][2] * b2f((unsigned short)(gv.y & 0xFFFF))
           + hval[tt][mt][3] * b2f((unsigned short)(gv.y >> 16));
      }
      s += __shfl_xor(s, 16, 64);
      s += __shfl_xor(s, 32, 64);
      if (l < 16) {
        int e = row - ag * 11;
        qout[n*17 + 6 + e] = s + qbv[tt] + hbuf[n] + hob_b0;
      }
    }
  }
}

extern "C" void kernel_launch(void* const* d_in, const int* in_sizes, int n_in,
                              void* d_out, int out_size, void* d_ws, size_t ws_size,
                              hipStream_t stream)
{
  (void)in_sizes; (void)n_in; (void)out_size; (void)ws_size;
  const float* own        = (const float*)d_in[0];
  const float* enemy      = (const float*)d_in[1];
  const float* ally       = (const float*)d_in[2];
  const float* hidden     = (const float*)d_in[3];
  const float* fc1_w      = (const float*)d_in[4];
  const float* fc1_b      = (const float*)d_in[5];
  const float* agent_emb  = (const float*)d_in[6];
  const float* action_emb = (const float*)d_in[7];
  const float* hen_win  = (const float*)d_in[8];  const float* hen_bin  = (const float*)d_in[9];
  const float* hen_wres = (const float*)d_in[10]; const float* hen_bres = (const float*)d_in[11];
  const float* hen_wout = (const float*)d_in[12]; const float* hen_bout = (const float*)d_in[13];
  const float* hal_win  = (const float*)d_in[14]; const float* hal_bin  = (const float*)d_in[15];
  const float* hal_wres = (const float*)d_in[16]; const float* hal_bres = (const float*)d_in[17];
  const float* hal_wout = (const float*)d_in[18]; const float* hal_bout = (const float*)d_in[19];
  const float* gru_wi = (const float*)d_in[20];   const float* gru_wh = (const float*)d_in[21];
  const float* gru_bi = (const float*)d_in[22];   const float* gru_bh = (const float*)d_in[23];
  const float* fc2_w  = (const float*)d_in[24];   const float* fc2_b  = (const float*)d_in[25];
  const float* how_win  = (const float*)d_in[26]; const float* how_bin  = (const float*)d_in[27];
  const float* how_wres = (const float*)d_in[28]; const float* how_bres = (const float*)d_in[29];
  const float* how_wout = (const float*)d_in[30]; const float* how_bout = (const float*)d_in[31];
  const float* hob_win  = (const float*)d_in[32]; const float* hob_bin  = (const float*)d_in[33];
  const float* hob_wres = (const float*)d_in[34]; const float* hob_bres = (const float*)d_in[35];
  const float* hob_wout = (const float*)d_in[36]; const float* hob_bout = (const float*)d_in[37];
  const int* agent_idx   = (const int*)d_in[38];
  const int* last_action = (const int*)d_in[39];

  unsigned short* ws = (unsigned short*)d_ws;
  float* emb_en = (float*)((char*)d_ws + B_EMB_EN);
  float* emb_al = (float*)((char*)d_ws + B_EMB_AL);
  float* hb     = (float*)((char*)d_ws + B_HB);
  unsigned short* g_bf = (unsigned short*)((char*)d_ws + B_GBF);

  float* q  = (float*)d_out;
  float* hh = q + 1024*10*17;

  kprep<<<128, 256, 0, stream>>>(hen_win, hen_wres, hal_win, hal_wres,
      how_win, how_wres, hob_win, hob_wres,
      hen_wout, hen_bout, hal_wout, hal_bout,
      gru_wi, gru_wh, fc1_w, fc2_w, how_bout, how_wout, hob_wout, ws);
  khyp_ea<<<1280, 256, 0, stream>>>(enemy, ally, ws,
      hen_bin, hen_bres, hal_bin, hal_bres, emb_en, emb_al);
  kfused<<<640, 256, 0, stream>>>(own, agent_emb, action_emb, agent_idx, last_action,
      emb_en, emb_al, hidden, ws, fc1_b, gru_bi, gru_bh, fc2_b, q, hh, g_bf, hb);
  kattack<<<640, 256, 0, stream>>>(enemy, ws, how_bin, how_bres, hob_bin, hob_bres,
      g_bf, hb, hob_wout, hob_bout, q);
}